// Round 1
// baseline (2049.188 us; speedup 1.0000x reference)
//
#include <hip/hip_runtime.h>
#include <math.h>

#define B_ 4
#define N_ 4096
#define DIM_ 768
#define H_ 12
#define HD_ 64
#define E_ 160
#define NC_ 32
#define NU_ 128
#define CH_ 3072
#define OH_ 768

__device__ __forceinline__ float wred_sum(float v) {
#pragma unroll
  for (int m = 32; m; m >>= 1) v += __shfl_xor(v, m);
  return v;
}

// ---------------- K1: slot queries -> qn_t[h][d][e] (LN + l2norm) -------------
__global__ __launch_bounds__(256) void k_qn(const float* __restrict__ phi,
                                            const float* __restrict__ qg,
                                            const float* __restrict__ qb,
                                            const float* __restrict__ lnw,
                                            const float* __restrict__ lnb,
                                            float* __restrict__ qn_t) {
  int gid = blockIdx.x * blockDim.x + threadIdx.x;
  int wid = gid >> 6, lane = gid & 63;
  if (wid >= H_ * E_) return;
  int h = wid / E_, e = wid % E_;
  float v = phi[e * DIM_ + h * HD_ + lane] * qg[lane] + qb[lane];
  float mean = wred_sum(v) * (1.0f / 64.0f);
  float c = v - mean;
  float var = wred_sum(c * c) * (1.0f / 64.0f);
  float xx = c / sqrtf(var + 1e-5f) * lnw[lane] + lnb[lane];
  float n2 = wred_sum(xx * xx);
  qn_t[h * (HD_ * E_) + lane * E_ + e] = xx / (sqrtf(n2) + 1e-6f);
}

// ---------------- K2: logits[b,h,n,e] = l2norm(k) . qn ----------------------
__global__ __launch_bounds__(256) void k_logits(const float* __restrict__ x,
                                                const float* __restrict__ kg,
                                                const float* __restrict__ kb,
                                                const float* __restrict__ qn_t,
                                                float* __restrict__ logits) {
  int n0 = blockIdx.x * 64;
  int h = blockIdx.y, b = blockIdx.z;
  __shared__ float kt[64 * 65];  // [d][tok], pad 65 -> conflict-free
  int t = threadIdx.x, lane = t & 63, w = t >> 6;
  for (int p = 0; p < 16; ++p) {
    int tok = (p << 2) | w;
    float v = x[((size_t)(b * N_ + n0 + tok)) * DIM_ + h * HD_ + lane] * kg[lane] + kb[lane];
    float s2 = wred_sum(v * v);
    kt[lane * 65 + tok] = v / (sqrtf(s2) + 1e-6f);
  }
  __syncthreads();
  int tok = lane, e0 = w * 40;
  float acc[40];
#pragma unroll
  for (int j = 0; j < 40; ++j) acc[j] = 0.0f;
  const float* qh = qn_t + h * (HD_ * E_) + e0;
  for (int d = 0; d < 64; ++d) {
    float kv = kt[d * 65 + tok];
    const float4* q4 = (const float4*)(qh + d * E_);  // broadcast (same addr all lanes)
#pragma unroll
    for (int j = 0; j < 10; ++j) {
      float4 q = q4[j];
      acc[4 * j + 0] = fmaf(kv, q.x, acc[4 * j + 0]);
      acc[4 * j + 1] = fmaf(kv, q.y, acc[4 * j + 1]);
      acc[4 * j + 2] = fmaf(kv, q.z, acc[4 * j + 2]);
      acc[4 * j + 3] = fmaf(kv, q.w, acc[4 * j + 3]);
    }
  }
  float* lrow = logits + (((size_t)(b * H_ + h)) * N_ + n0 + tok) * E_ + e0;
#pragma unroll
  for (int j = 0; j < 10; ++j)
    ((float4*)lrow)[j] = make_float4(acc[4 * j], acc[4 * j + 1], acc[4 * j + 2], acc[4 * j + 3]);
}

// ------- K3: slots_un[b,h,e,d] = sum_n exp(l/s0)*x ; sumexp[b,h,e] ----------
__global__ __launch_bounds__(256) void k_slots(const float* __restrict__ x,
                                               const float* __restrict__ logits,
                                               const float* __restrict__ s0p,
                                               float* __restrict__ slots_un,
                                               float* __restrict__ sumexp) {
  int c = blockIdx.x, h = blockIdx.y, b = blockIdx.z;
  int n0 = c * 256;
  float inv_s0 = 1.0f / s0p[0];
  __shared__ __align__(16) float w_s[160];
  __shared__ float se_s[160];
  int t = threadIdx.x, d = t & 63, e0 = (t >> 6) * 40;
  if (t < 160) se_s[t] = 0.0f;
  float acc[40];
#pragma unroll
  for (int j = 0; j < 40; ++j) acc[j] = 0.0f;
  const float* lbase = logits + (((size_t)(b * H_ + h)) * N_ + n0) * E_;
  const float* xbase = x + ((size_t)(b * N_ + n0)) * DIM_ + h * HD_ + d;
  __syncthreads();
  for (int i = 0; i < 256; ++i) {
    if (t < 160) {
      float wv = expf(lbase[(size_t)i * E_ + t] * inv_s0);
      w_s[t] = wv;
      se_s[t] += wv;
    }
    __syncthreads();
    float xv = xbase[(size_t)i * DIM_];
    const float4* w4 = (const float4*)(w_s + e0);  // broadcast reads
#pragma unroll
    for (int j = 0; j < 10; ++j) {
      float4 q = w4[j];
      acc[4 * j + 0] = fmaf(q.x, xv, acc[4 * j + 0]);
      acc[4 * j + 1] = fmaf(q.y, xv, acc[4 * j + 1]);
      acc[4 * j + 2] = fmaf(q.z, xv, acc[4 * j + 2]);
      acc[4 * j + 3] = fmaf(q.w, xv, acc[4 * j + 3]);
    }
    __syncthreads();
  }
  float* sp = slots_un + (((size_t)(b * H_ + h)) * E_ + e0) * HD_ + d;
#pragma unroll
  for (int j = 0; j < 40; ++j) atomicAdd(sp + j * HD_, acc[j]);
  if (t < 160) atomicAdd(sumexp + (b * H_ + h) * E_ + t, se_s[t]);
}

// ---------------- K4a: core expert layer1 (pre-activation, d-split) ----------
__global__ __launch_bounds__(256) void k_core1(const float* __restrict__ slots_un,
                                               const float* __restrict__ sumexp,
                                               const float* __restrict__ w1,
                                               float* __restrict__ pre) {
  int dc = blockIdx.x, hhc = blockIdx.y, e = blockIdx.z;
  int t = threadIdx.x;
  __shared__ float slot_s[384];  // [b][96]
  for (int o = t; o < 384; o += 256) {
    int b = o / 96, jj = o % 96;
    int j = dc * 96 + jj, h = j >> 6, d = j & 63;
    slot_s[o] = slots_un[(((size_t)(b * H_ + h)) * E_ + e) * HD_ + d] /
                sumexp[(b * H_ + h) * E_ + e];
  }
  __syncthreads();
  int hh = hhc * 1024 + t * 4;
  float a[4][4];
#pragma unroll
  for (int bb = 0; bb < 4; ++bb)
#pragma unroll
    for (int k = 0; k < 4; ++k) a[bb][k] = 0.0f;
  const float* wp = w1 + ((size_t)(e * DIM_ + dc * 96)) * CH_ + hh;
  for (int jj = 0; jj < 96; ++jj) {
    float4 wv = *(const float4*)(wp + (size_t)jj * CH_);
#pragma unroll
    for (int bb = 0; bb < 4; ++bb) {
      float sv = slot_s[bb * 96 + jj];
      a[bb][0] = fmaf(sv, wv.x, a[bb][0]);
      a[bb][1] = fmaf(sv, wv.y, a[bb][1]);
      a[bb][2] = fmaf(sv, wv.z, a[bb][2]);
      a[bb][3] = fmaf(sv, wv.w, a[bb][3]);
    }
  }
#pragma unroll
  for (int bb = 0; bb < 4; ++bb) {
    float* pp = pre + (size_t)(e * 4 + bb) * CH_ + hh;
    atomicAdd(pp + 0, a[bb][0]);
    atomicAdd(pp + 1, a[bb][1]);
    atomicAdd(pp + 2, a[bb][2]);
    atomicAdd(pp + 3, a[bb][3]);
  }
}

// ---------------- K4b: occ expert layer1 -------------------------------------
__global__ __launch_bounds__(192) void k_occ1(const float* __restrict__ slots_un,
                                              const float* __restrict__ sumexp,
                                              const float* __restrict__ w1,
                                              float* __restrict__ pre) {
  int dc = blockIdx.x, e = blockIdx.y;
  int t = threadIdx.x;
  __shared__ float slot_s[384];
  for (int o = t; o < 384; o += 192) {
    int b = o / 96, jj = o % 96;
    int j = dc * 96 + jj, h = j >> 6, d = j & 63;
    int eg = NC_ + e;
    slot_s[o] = slots_un[(((size_t)(b * H_ + h)) * E_ + eg) * HD_ + d] /
                sumexp[(b * H_ + h) * E_ + eg];
  }
  __syncthreads();
  int hh = t * 4;
  float a[4][4];
#pragma unroll
  for (int bb = 0; bb < 4; ++bb)
#pragma unroll
    for (int k = 0; k < 4; ++k) a[bb][k] = 0.0f;
  const float* wp = w1 + ((size_t)(e * DIM_ + dc * 96)) * OH_ + hh;
  for (int jj = 0; jj < 96; ++jj) {
    float4 wv = *(const float4*)(wp + (size_t)jj * OH_);
#pragma unroll
    for (int bb = 0; bb < 4; ++bb) {
      float sv = slot_s[bb * 96 + jj];
      a[bb][0] = fmaf(sv, wv.x, a[bb][0]);
      a[bb][1] = fmaf(sv, wv.y, a[bb][1]);
      a[bb][2] = fmaf(sv, wv.z, a[bb][2]);
      a[bb][3] = fmaf(sv, wv.w, a[bb][3]);
    }
  }
#pragma unroll
  for (int bb = 0; bb < 4; ++bb) {
    float* pp = pre + (size_t)(e * 4 + bb) * OH_ + hh;
    atomicAdd(pp + 0, a[bb][0]);
    atomicAdd(pp + 1, a[bb][1]);
    atomicAdd(pp + 2, a[bb][2]);
    atomicAdd(pp + 3, a[bb][3]);
  }
}

__device__ __forceinline__ float gelu_exact(float v) {
  return v * 0.5f * (1.0f + erff(v * 0.70710678118654752f));
}

// ---------------- K5a: core expert layer2 (hh-split) -------------------------
__global__ __launch_bounds__(192) void k_core2(const float* __restrict__ pre,
                                               const float* __restrict__ b1,
                                               const float* __restrict__ w2,
                                               float* __restrict__ eo) {
  int hc = blockIdx.x, e = blockIdx.y;
  int t = threadIdx.x;
  __shared__ float hid_s[512];  // [b][128]
  for (int o = t; o < 512; o += 192) {
    int b = o >> 7, jj = o & 127;
    int hh = hc * 128 + jj;
    float v = pre[(size_t)(e * 4 + b) * CH_ + hh] + b1[e * CH_ + hh];
    hid_s[o] = gelu_exact(v);
  }
  __syncthreads();
  int dj = t * 4;
  float a[4][4];
#pragma unroll
  for (int bb = 0; bb < 4; ++bb)
#pragma unroll
    for (int k = 0; k < 4; ++k) a[bb][k] = 0.0f;
  const float* wp = w2 + ((size_t)(e * CH_ + hc * 128)) * DIM_ + dj;
  for (int jj = 0; jj < 128; ++jj) {
    float4 wv = *(const float4*)(wp + (size_t)jj * DIM_);
#pragma unroll
    for (int bb = 0; bb < 4; ++bb) {
      float hv = hid_s[bb * 128 + jj];
      a[bb][0] = fmaf(hv, wv.x, a[bb][0]);
      a[bb][1] = fmaf(hv, wv.y, a[bb][1]);
      a[bb][2] = fmaf(hv, wv.z, a[bb][2]);
      a[bb][3] = fmaf(hv, wv.w, a[bb][3]);
    }
  }
#pragma unroll
  for (int bb = 0; bb < 4; ++bb) {
    float* op = eo + ((size_t)(bb * E_ + e)) * DIM_ + dj;
    atomicAdd(op + 0, a[bb][0]);
    atomicAdd(op + 1, a[bb][1]);
    atomicAdd(op + 2, a[bb][2]);
    atomicAdd(op + 3, a[bb][3]);
  }
}

// ---------------- K5b: occ expert layer2 -------------------------------------
__global__ __launch_bounds__(192) void k_occ2(const float* __restrict__ pre,
                                              const float* __restrict__ b1,
                                              const float* __restrict__ w2,
                                              float* __restrict__ eo) {
  int hc = blockIdx.x, e = blockIdx.y;
  int t = threadIdx.x;
  __shared__ float hid_s[384];  // [b][96]
  for (int o = t; o < 384; o += 192) {
    int b = o / 96, jj = o % 96;
    int hh = hc * 96 + jj;
    float v = pre[(size_t)(e * 4 + b) * OH_ + hh] + b1[e * OH_ + hh];
    hid_s[o] = gelu_exact(v);
  }
  __syncthreads();
  int dj = t * 4;
  float a[4][4];
#pragma unroll
  for (int bb = 0; bb < 4; ++bb)
#pragma unroll
    for (int k = 0; k < 4; ++k) a[bb][k] = 0.0f;
  const float* wp = w2 + ((size_t)(e * OH_ + hc * 96)) * DIM_ + dj;
  for (int jj = 0; jj < 96; ++jj) {
    float4 wv = *(const float4*)(wp + (size_t)jj * DIM_);
#pragma unroll
    for (int bb = 0; bb < 4; ++bb) {
      float hv = hid_s[bb * 96 + jj];
      a[bb][0] = fmaf(hv, wv.x, a[bb][0]);
      a[bb][1] = fmaf(hv, wv.y, a[bb][1]);
      a[bb][2] = fmaf(hv, wv.z, a[bb][2]);
      a[bb][3] = fmaf(hv, wv.w, a[bb][3]);
    }
  }
#pragma unroll
  for (int bb = 0; bb < 4; ++bb) {
    float* op = eo + ((size_t)(bb * E_ + NC_ + e)) * DIM_ + dj;
    atomicAdd(op + 0, a[bb][0]);
    atomicAdd(op + 1, a[bb][1]);
    atomicAdd(op + 2, a[bb][2]);
    atomicAdd(op + 3, a[bb][3]);
  }
}

// -------- K6: entmax1.5 (Newton root-find) + sparse combine -> out -----------
__global__ __launch_bounds__(256) void k_out(const float* __restrict__ logits,
                                             const float* __restrict__ eo,
                                             const float* __restrict__ cb2,
                                             const float* __restrict__ ob2,
                                             const float* __restrict__ s1p,
                                             float* __restrict__ out) {
  int tile = blockIdx.x, h = blockIdx.y, b = blockIdx.z;
  int t = threadIdx.x, lane = t & 63, w = t >> 6;
  __shared__ float eo_s[160 * 64];  // [e][d]
  for (int o = t; o < 160 * 64; o += 256) {
    int e = o >> 6, d = o & 63, dim = h * HD_ + d;
    float bias = (e < NC_) ? cb2[e * DIM_ + dim] : ob2[(e - NC_) * DIM_ + dim];
    eo_s[o] = eo[((size_t)(b * E_ + e)) * DIM_ + dim] + bias;
  }
  __syncthreads();
  float inv_s1 = 1.0f / s1p[0];
  for (int i = 0; i < 4; ++i) {
    int n = tile * 16 + (i << 2) + w;  // one wave per token
    const float* lrow = logits + (((size_t)(b * H_ + h)) * N_ + n) * E_;
    float z0 = lrow[lane] * inv_s1;
    float z1 = lrow[64 + lane] * inv_s1;
    float z2 = (lane < 32) ? lrow[128 + lane] * inv_s1 : -INFINITY;
    float m = fmaxf(z0, fmaxf(z1, z2));
#pragma unroll
    for (int mm = 32; mm; mm >>= 1) m = fmaxf(m, __shfl_xor(m, mm));
    float x0 = (z0 - m) * 0.5f, x1 = (z1 - m) * 0.5f, x2 = (z2 - m) * 0.5f;
    // tau: root of sum(max(x - tau, 0)^2) = 1; Newton from tau=-1 is monotone.
    float tau = -1.0f;
#pragma unroll
    for (int it = 0; it < 12; ++it) {
      float c0 = fmaxf(x0 - tau, 0.0f);
      float c1 = fmaxf(x1 - tau, 0.0f);
      float c2 = fmaxf(x2 - tau, 0.0f);
      float f = c0 * c0 + c1 * c1 + c2 * c2;
      float g = c0 + c1 + c2;
#pragma unroll
      for (int mm = 32; mm; mm >>= 1) {
        f += __shfl_xor(f, mm);
        g += __shfl_xor(g, mm);
      }
      tau += (f - 1.0f) / (2.0f * g);  // g >= 1 near root; never 0
    }
    float c0 = fmaxf(x0 - tau, 0.0f), p0 = c0 * c0;
    float c1 = fmaxf(x1 - tau, 0.0f), p1 = c1 * c1;
    float c2 = fmaxf(x2 - tau, 0.0f), p2 = c2 * c2;
    float acc = 0.0f;
    unsigned long long mm0 = __ballot(p0 > 0.0f);
    while (mm0) {
      int src = __ffsll(mm0) - 1;
      mm0 &= mm0 - 1;
      acc = fmaf(__shfl(p0, src), eo_s[src * 64 + lane], acc);
    }
    unsigned long long mm1 = __ballot(p1 > 0.0f);
    while (mm1) {
      int src = __ffsll(mm1) - 1;
      mm1 &= mm1 - 1;
      acc = fmaf(__shfl(p1, src), eo_s[(64 + src) * 64 + lane], acc);
    }
    unsigned long long mm2 = __ballot(p2 > 0.0f);
    while (mm2) {
      int src = __ffsll(mm2) - 1;
      mm2 &= mm2 - 1;
      acc = fmaf(__shfl(p2, src), eo_s[(128 + src) * 64 + lane], acc);
    }
    out[((size_t)(b * N_ + n)) * DIM_ + h * HD_ + lane] = acc;
  }
}

extern "C" void kernel_launch(void* const* d_in, const int* in_sizes, int n_in,
                              void* d_out, int out_size, void* d_ws, size_t ws_size,
                              hipStream_t stream) {
  const float* x = (const float*)d_in[0];
  const float* phi = (const float*)d_in[1];
  const float* kg = (const float*)d_in[2];
  const float* kb = (const float*)d_in[3];
  const float* qg = (const float*)d_in[4];
  const float* qb = (const float*)d_in[5];
  const float* lnw = (const float*)d_in[6];
  const float* lnb = (const float*)d_in[7];
  const float* s0 = (const float*)d_in[8];
  const float* s1 = (const float*)d_in[9];
  const float* cw1 = (const float*)d_in[10];
  const float* cb1 = (const float*)d_in[11];
  const float* cw2 = (const float*)d_in[12];
  const float* cb2 = (const float*)d_in[13];
  const float* ow1 = (const float*)d_in[14];
  const float* ob1 = (const float*)d_in[15];
  const float* ow2 = (const float*)d_in[16];
  const float* ob2 = (const float*)d_in[17];
  float* out = (float*)d_out;

  float* ws = (float*)d_ws;
  float* slots_un = ws;                      // 491520
  float* sumexp = slots_un + 491520;         // 7680
  float* core_pre = sumexp + 7680;           // 393216  [e][b][hh]
  float* occ_pre = core_pre + 393216;        // 393216  [e][b][hh]
  float* eo_pre = occ_pre + 393216;          // 491520  [b][e][dim]
  float* qn_t = eo_pre + 491520;             // 122880  [h][d][e]
  float* logits = qn_t + 122880;             // 31457280 [b][h][n][e]

  // zero the accumulated buffers (slots_un..eo_pre contiguous)
  hipMemsetAsync(slots_un, 0, (size_t)1777152 * 4, stream);

  k_qn<<<480, 256, 0, stream>>>(phi, qg, qb, lnw, lnb, qn_t);
  k_logits<<<dim3(64, 12, 4), 256, 0, stream>>>(x, kg, kb, qn_t, logits);
  k_slots<<<dim3(16, 12, 4), 256, 0, stream>>>(x, logits, s0, slots_un, sumexp);
  k_core1<<<dim3(8, 3, 32), 256, 0, stream>>>(slots_un, sumexp, cw1, core_pre);
  k_occ1<<<dim3(8, 128), 192, 0, stream>>>(slots_un, sumexp, ow1, occ_pre);
  k_core2<<<dim3(24, 32), 192, 0, stream>>>(core_pre, cb1, cw2, eo_pre);
  k_occ2<<<dim3(8, 128), 192, 0, stream>>>(occ_pre, ob1, ow2, eo_pre);
  k_out<<<dim3(256, 12, 4), 256, 0, stream>>>(logits, eo_pre, cb2, ob2, s1, out);
}